// Round 1
// 264.531 us; speedup vs baseline: 1.3812x; 1.3812x over previous
//
#include <hip/hip_runtime.h>

// Batched thin QR (LAPACK sign convention) for 8192 x (256x16) fp32.
// One 64-lane wave per matrix; lane l owns rows {l, l+64, l+128, l+192}.
//
// Round-4: algorithm restructure for latency + occupancy.
//   X = B*C with B=[[I16,0],[0,Uhat]] orthonormal, C=[X_top; chol(X_bot'X_bot)].
//   Householder on the 32x16 C yields the SAME pivots/alphas/R (incl. LAPACK
//   signs) as on X (rows<=16 of B are e_j; reflectors map v_X = B v_C).
//   Then Q = X R^{-1} by register-only forward elimination.
//   - Gram (136 reductions) is one independent, pipelined wave_sum64 batch.
//   - chol + small-HH + solve use readlane broadcasts + 5-stage 32-lane DPP
//     sums: the only sequential phases, and they are tiny.
//   - NO LDS at all; uniforms live in SGPRs via readlane.
//   - __launch_bounds__(256,4) forces VGPR<=128 -> 4 waves/SIMD (was 2 @ 208).

constexpr int BATCH = 8192;
constexpr int DROWS = 256;
constexpr int QC    = 16;

__device__ __forceinline__ float rdlane(float v, int l) {
    return __int_as_float(__builtin_amdgcn_readlane(__float_as_int(v), l));
}

template <int CTRL>
__device__ __forceinline__ float dpp_add(float x) {
    int y = __builtin_amdgcn_update_dpp(0, __float_as_int(x), CTRL, 0xf, 0xf, true);
    return x + __int_as_float(y);
}

// Full 64-lane sum -> wave-uniform (lane 63 holds it after bcast chain).
__device__ __forceinline__ float wave_sum64(float x) {
    x = dpp_add<0xB1>(x);   // xor 1
    x = dpp_add<0x4E>(x);   // xor 2
    x = dpp_add<0x141>(x);  // row_half_mirror : 8-group sums
    x = dpp_add<0x140>(x);  // row_mirror      : 16-row sums
    x = dpp_add<0x142>(x);  // row_bcast15     : lanes16-31 = rows0+1
    x = dpp_add<0x143>(x);  // row_bcast31     : lanes48-63 = full
    return rdlane(x, 63);
}

// Sum over lanes 0..31 (lanes >=32 must carry zeros) -> wave-uniform.
__device__ __forceinline__ float wave_sum32(float x) {
    x = dpp_add<0xB1>(x);
    x = dpp_add<0x4E>(x);
    x = dpp_add<0x141>(x);
    x = dpp_add<0x140>(x);  // each 16-row has its row sum
    x = dpp_add<0x142>(x);  // lanes16-31 = rows0+1 = sum over lanes 0..31
    return rdlane(x, 31);
}

__global__ __launch_bounds__(256, 4) void qr_cholhh_kernel(
    const float* __restrict__ in, float* __restrict__ out)
{
    const int lane = threadIdx.x & 63;
    const int wid  = threadIdx.x >> 6;
    const int b    = blockIdx.x * 4 + wid;

    const float4* __restrict__ A4 = (const float4*)(in  + (size_t)b * (DROWS * QC));
    float4*       __restrict__ O4 = (float4*)      (out + (size_t)b * (DROWS * QC));

    float x[4][QC];   // the matrix; becomes Q at the end

    // ---- load ----
#pragma unroll
    for (int s = 0; s < 4; ++s) {
        const int rr = s * 64 + lane;
#pragma unroll
        for (int q4 = 0; q4 < 4; ++q4) {
            float4 t = A4[rr * 4 + q4];
            x[s][q4*4+0] = t.x; x[s][q4*4+1] = t.y;
            x[s][q4*4+2] = t.z; x[s][q4*4+3] = t.w;
        }
    }

    const int li = lane - 16;   // cholesky row index for lanes 16..31

    // slot-0 copies with global rows 0..15 zeroed (mask one Gram operand)
    float xm[QC];
#pragma unroll
    for (int i = 0; i < QC; ++i) xm[i] = (lane < 16) ? 0.f : x[0][i];

    // ---- G_bot = X[16:,:]^T X[16:,:] : 136 independent pipelined reductions.
    //      Place G_bot[i][j] into lane (16+i)'s g[j] and lane (16+j)'s g[i]. ----
    float g[QC];
#pragma unroll
    for (int i = 0; i < QC; ++i) g[i] = 0.f;

#pragma unroll
    for (int j = 0; j < QC; ++j) {
#pragma unroll
        for (int i = 0; i <= j; ++i) {
            float p = fmaf(x[3][i], x[3][j],
                      fmaf(x[2][i], x[2][j],
                      fmaf(x[1][i], x[1][j], xm[i] * x[0][j])));
            const float sv = wave_sum64(p);
            g[j] = (li == i) ? sv : g[j];
            if (i != j) g[i] = (li == j) ? sv : g[i];
        }
    }

    // ---- Cholesky of G_bot (rows in lanes 16..31, full symmetric working set).
    //      Symmetry trick: A[k][i] needed by row i is lane i's own g[k].
    //      Rows left unscaled; per-row scale rs = 1/sqrt(piv) applied at C build. ----
    float rs = 0.f;
#pragma unroll
    for (int k = 0; k < QC; ++k) {
        const float piv = rdlane(g[k], 16 + k);          // A^(k)[k][k]
        const float inv = __builtin_amdgcn_rcpf(piv);
        const float rsk = __builtin_amdgcn_rsqf(piv);
        rs = (li == k) ? rsk : rs;
        const float m = (li > k) ? g[k] * inv : 0.f;     // frozen rows -> no-op
#pragma unroll
        for (int j = k + 1; j < QC; ++j) {
            const float bj = rdlane(g[j], 16 + k);       // A^(k)[k][j] broadcast
            g[j] = fmaf(-m, bj, g[j]);
        }
    }

    // ---- C = [X_top ; U] in lanes 0..31 (lanes >=32 exactly zero) ----
    float c[QC];
#pragma unroll
    for (int t = 0; t < QC; ++t) {
        const float ub = (li <= t) ? g[t] * rs : 0.f;    // upper-tri chol row
        c[t] = (lane < 16) ? x[0][t] : ub;               // lanes>=32: li>15 -> 0
    }

    // column norms^2 of C (== column norms of X); downdated as rows freeze
    float nrm2[QC];
#pragma unroll
    for (int t = 0; t < QC; ++t) nrm2[t] = wave_sum32(c[t] * c[t]);

    // ---- Householder on C (32x16): leaves R embedded in c[] (lane r = row r) ----
#pragma unroll
    for (int j = 0; j < QC; ++j) {
        const float piv   = rdlane(c[j], j);
        const float nrm   = sqrtf(nrm2[j]);
        const float alpha = -copysignf(nrm, piv);            // LAPACK dlarfg sign
        const float vtv   = 2.f * (nrm2[j] - alpha * piv);   // ||v||^2, no cancel
        const float beta  = 2.f * __builtin_amdgcn_rcpf(vtv);
        // reflector (kept out of c[j] so frozen R rows i<j stay intact)
        const float v = (lane < j) ? 0.f : ((lane == j) ? piv - alpha : c[j]);
#pragma unroll
        for (int t = j + 1; t < QC; ++t) {
            const float d  = wave_sum32(v * c[t]);
            const float wb = beta * d;
            c[t] = fmaf(-wb, v, c[t]);
            const float rv = rdlane(c[t], j);                // R[j][t] frozen now
            nrm2[t] = fmaf(-rv, rv, nrm2[t]);
        }
        c[j] = (lane == j) ? alpha : c[j];                   // R[j][j]
    }

    // ---- Q = X R^{-1}: forward elimination, all-register, R via readlane ----
#pragma unroll
    for (int k = 0; k < QC; ++k) {
        const float rkk = rdlane(c[k], k);
        const float ikk = __builtin_amdgcn_rcpf(rkk);
        x[0][k] *= ikk; x[1][k] *= ikk; x[2][k] *= ikk; x[3][k] *= ikk;
#pragma unroll
        for (int t = k + 1; t < QC; ++t) {
            const float r = rdlane(c[t], k);                 // R[k][t]
            x[0][t] = fmaf(-r, x[0][k], x[0][t]);
            x[1][t] = fmaf(-r, x[1][k], x[1][t]);
            x[2][t] = fmaf(-r, x[2][k], x[2][t]);
            x[3][t] = fmaf(-r, x[3][k], x[3][t]);
        }
    }

    // ---- store ----
#pragma unroll
    for (int s = 0; s < 4; ++s) {
        const int rr = s * 64 + lane;
#pragma unroll
        for (int q4 = 0; q4 < 4; ++q4) {
            O4[rr * 4 + q4] = make_float4(x[s][q4*4+0], x[s][q4*4+1],
                                          x[s][q4*4+2], x[s][q4*4+3]);
        }
    }
}

extern "C" void kernel_launch(void* const* d_in, const int* in_sizes, int n_in,
                              void* d_out, int out_size, void* d_ws, size_t ws_size,
                              hipStream_t stream) {
    const float* X = (const float*)d_in[0];
    float*       O = (float*)d_out;
    qr_cholhh_kernel<<<BATCH / 4, 256, 0, stream>>>(X, O);
}

// Round 3
// 253.070 us; speedup vs baseline: 1.4438x; 1.0453x over previous
//
#include <hip/hip_runtime.h>

// Batched thin QR (LAPACK sign convention) for 8192 x (256x16) fp32.
// One 64-lane wave per matrix; lane l owns rows {l, l+64, l+128, l+192}.
//
// Round-6: resubmit of round-5 (infra failure, no counters returned).
//   Round-4 counters showed VGPR_Count=64: the compiler chased 8 waves/SIMD by
//   REMATERIALIZING x[4][16] (re-issuing global loads) instead of keeping the
//   matrix resident -> +12MB HBM refetch, inflated VALU stream, VALUBusy 57%.
//   The kernel's live set is ~110 regs and its unrolled Gram batch has huge
//   straight-line ILP, so 4 waves/SIMD with everything resident beats 8 waves
//   with remat. amdgpu_waves_per_eu(4,4) pins the budget at 128 VGPRs.
//   Algorithm unchanged from round-4 (verified, absmax 9.77e-4):
//     X = B*C, B=[[I16,0],[0,Uhat]], C=[X_top; chol(X_bot'X_bot)];
//     Householder on 32x16 C reproduces LAPACK pivots/signs/R exactly;
//     Q = X R^{-1} by register-only forward elimination. No LDS.

constexpr int BATCH = 8192;
constexpr int DROWS = 256;
constexpr int QC    = 16;

__device__ __forceinline__ float rdlane(float v, int l) {
    return __int_as_float(__builtin_amdgcn_readlane(__float_as_int(v), l));
}

template <int CTRL>
__device__ __forceinline__ float dpp_add(float x) {
    int y = __builtin_amdgcn_update_dpp(0, __float_as_int(x), CTRL, 0xf, 0xf, true);
    return x + __int_as_float(y);
}

// Full 64-lane sum -> wave-uniform (lane 63 holds it after bcast chain).
__device__ __forceinline__ float wave_sum64(float x) {
    x = dpp_add<0xB1>(x);   // xor 1
    x = dpp_add<0x4E>(x);   // xor 2
    x = dpp_add<0x141>(x);  // row_half_mirror : 8-group sums
    x = dpp_add<0x140>(x);  // row_mirror      : 16-row sums
    x = dpp_add<0x142>(x);  // row_bcast15     : lanes16-31 = rows0+1
    x = dpp_add<0x143>(x);  // row_bcast31     : lanes48-63 = full
    return rdlane(x, 63);
}

// Sum over lanes 0..31 (lanes >=32 must carry zeros) -> wave-uniform.
__device__ __forceinline__ float wave_sum32(float x) {
    x = dpp_add<0xB1>(x);
    x = dpp_add<0x4E>(x);
    x = dpp_add<0x141>(x);
    x = dpp_add<0x140>(x);  // each 16-row has its row sum
    x = dpp_add<0x142>(x);  // lanes16-31 = sum over lanes 0..31
    return rdlane(x, 31);
}

__global__ __attribute__((amdgpu_waves_per_eu(4, 4)))
__launch_bounds__(256) void qr_cholhh_r6(
    const float* __restrict__ in, float* __restrict__ out)
{
    const int lane = threadIdx.x & 63;
    const int wid  = threadIdx.x >> 6;
    const int b    = blockIdx.x * 4 + wid;

    const float4* __restrict__ A4 = (const float4*)(in  + (size_t)b * (DROWS * QC));
    float4*       __restrict__ O4 = (float4*)      (out + (size_t)b * (DROWS * QC));

    float x[4][QC];   // the matrix; becomes Q at the end

    // ---- load ----
#pragma unroll
    for (int s = 0; s < 4; ++s) {
        const int rr = s * 64 + lane;
#pragma unroll
        for (int q4 = 0; q4 < 4; ++q4) {
            float4 t = A4[rr * 4 + q4];
            x[s][q4*4+0] = t.x; x[s][q4*4+1] = t.y;
            x[s][q4*4+2] = t.z; x[s][q4*4+3] = t.w;
        }
    }

    const int li = lane - 16;   // cholesky row index for lanes 16..31

    // slot-0 copies with global rows 0..15 zeroed (mask one Gram operand)
    float xm[QC];
#pragma unroll
    for (int i = 0; i < QC; ++i) xm[i] = (lane < 16) ? 0.f : x[0][i];

    // ---- G_bot = X[16:,:]^T X[16:,:] : 136 independent pipelined reductions.
    //      Place G_bot[i][j] into lane (16+i)'s g[j] and lane (16+j)'s g[i]. ----
    float g[QC];
#pragma unroll
    for (int i = 0; i < QC; ++i) g[i] = 0.f;

#pragma unroll
    for (int j = 0; j < QC; ++j) {
        const bool mj = (li == j);   // hoisted: reused for all i<j scatters
#pragma unroll
        for (int i = 0; i <= j; ++i) {
            float p = fmaf(x[3][i], x[3][j],
                      fmaf(x[2][i], x[2][j],
                      fmaf(x[1][i], x[1][j], xm[i] * x[0][j])));
            const float sv = wave_sum64(p);
            g[j] = (li == i) ? sv : g[j];
            if (i != j) g[i] = mj ? sv : g[i];
        }
    }

    // ---- Cholesky of G_bot (rows in lanes 16..31, full symmetric working set).
    //      Symmetry trick: A[k][i] needed by row i is lane i's own g[k].
    //      Rows left unscaled; per-row scale rs = 1/sqrt(piv) applied at C build. ----
    float rs = 0.f;
#pragma unroll
    for (int k = 0; k < QC; ++k) {
        const float piv = rdlane(g[k], 16 + k);          // A^(k)[k][k]
        const float inv = __builtin_amdgcn_rcpf(piv);
        const float rsk = __builtin_amdgcn_rsqf(piv);
        rs = (li == k) ? rsk : rs;
        const float m = (li > k) ? g[k] * inv : 0.f;     // frozen rows -> no-op
#pragma unroll
        for (int j = k + 1; j < QC; ++j) {
            const float bj = rdlane(g[j], 16 + k);       // A^(k)[k][j] broadcast
            g[j] = fmaf(-m, bj, g[j]);
        }
    }

    // ---- C = [X_top ; U] in lanes 0..31 (lanes >=32 exactly zero) ----
    float c[QC];
#pragma unroll
    for (int t = 0; t < QC; ++t) {
        const float ub = (li <= t) ? g[t] * rs : 0.f;    // upper-tri chol row
        c[t] = (lane < 16) ? x[0][t] : ub;               // lanes>=32: li>15 -> 0
    }

    // column norms^2 of C (== column norms of X); downdated as rows freeze
    float nrm2[QC];
#pragma unroll
    for (int t = 0; t < QC; ++t) nrm2[t] = wave_sum32(c[t] * c[t]);

    // ---- Householder on C (32x16): leaves R embedded in c[] (lane r = row r) ----
#pragma unroll
    for (int j = 0; j < QC; ++j) {
        const float piv   = rdlane(c[j], j);
        const float nrm   = sqrtf(nrm2[j]);
        const float alpha = -copysignf(nrm, piv);            // LAPACK dlarfg sign
        const float vtv   = 2.f * (nrm2[j] - alpha * piv);   // ||v||^2, no cancel
        const float beta  = 2.f * __builtin_amdgcn_rcpf(vtv);
        // reflector (kept out of c[j] so frozen R rows i<j stay intact)
        const float v = (lane < j) ? 0.f : ((lane == j) ? piv - alpha : c[j]);
#pragma unroll
        for (int t = j + 1; t < QC; ++t) {
            const float d  = wave_sum32(v * c[t]);
            const float wb = beta * d;
            c[t] = fmaf(-wb, v, c[t]);
            const float rv = rdlane(c[t], j);                // R[j][t] frozen now
            nrm2[t] = fmaf(-rv, rv, nrm2[t]);
        }
        c[j] = (lane == j) ? alpha : c[j];                   // R[j][j]
    }

    // ---- Q = X R^{-1}: forward elimination, all-register, R via readlane ----
#pragma unroll
    for (int k = 0; k < QC; ++k) {
        const float rkk = rdlane(c[k], k);
        const float ikk = __builtin_amdgcn_rcpf(rkk);
        x[0][k] *= ikk; x[1][k] *= ikk; x[2][k] *= ikk; x[3][k] *= ikk;
#pragma unroll
        for (int t = k + 1; t < QC; ++t) {
            const float r = rdlane(c[t], k);                 // R[k][t]
            x[0][t] = fmaf(-r, x[0][k], x[0][t]);
            x[1][t] = fmaf(-r, x[1][k], x[1][t]);
            x[2][t] = fmaf(-r, x[2][k], x[2][t]);
            x[3][t] = fmaf(-r, x[3][k], x[3][t]);
        }
    }

    // ---- store ----
#pragma unroll
    for (int s = 0; s < 4; ++s) {
        const int rr = s * 64 + lane;
#pragma unroll
        for (int q4 = 0; q4 < 4; ++q4) {
            O4[rr * 4 + q4] = make_float4(x[s][q4*4+0], x[s][q4*4+1],
                                          x[s][q4*4+2], x[s][q4*4+3]);
        }
    }
}

extern "C" void kernel_launch(void* const* d_in, const int* in_sizes, int n_in,
                              void* d_out, int out_size, void* d_ws, size_t ws_size,
                              hipStream_t stream) {
    const float* X = (const float*)d_in[0];
    float*       O = (float*)d_out;
    qr_cholhh_r6<<<BATCH / 4, 256, 0, stream>>>(X, O);
}

// Round 4
// 245.561 us; speedup vs baseline: 1.4879x; 1.0306x over previous
//
#include <hip/hip_runtime.h>

// Batched thin QR (LAPACK sign convention) for 8192 x (256x16) fp32.
// One 64-lane wave per matrix; lane l owns rows {l, l+64, l+128, l+192}.
//
// Round-7: move the Gram matrix to the MFMA pipe.
//   G_bot = Xm^T Xm (Xm = X with rows<16 zeroed) is a 16x16x256 matmul ->
//   v_mfma_f32_16x16x32_f16, split precision: v = h + l (two f16 planes),
//   hh+hl+lh+ll = (v-rho1)(v-rho2), rho <= 2^-22|v|  => G err ~2e-5 abs,
//   same class as the previous fp32 DPP-sum Gram (pivot signs preserved).
//   Robust-by-construction: A-frag==B-frag (k-perm cancels), G symmetric
//   (C/D transpose harmless), row-mask applied by value at staging.
//   Staging: per-wave LDS u16 planes, col-major pitch 72 (b128-aligned,
//   ~2-way banks). No barriers (per-wave in-order DS); asm fences guard
//   the type-punned buffer reuse. Chol/HH/solve unchanged from round-4.

constexpr int BATCH = 8192;
constexpr int DROWS = 256;
constexpr int QC    = 16;

typedef _Float16 half8 __attribute__((ext_vector_type(8)));
typedef float    f32x4 __attribute__((ext_vector_type(4)));

__device__ __forceinline__ float rdlane(float v, int l) {
    return __int_as_float(__builtin_amdgcn_readlane(__float_as_int(v), l));
}

template <int CTRL>
__device__ __forceinline__ float dpp_add(float x) {
    int y = __builtin_amdgcn_update_dpp(0, __float_as_int(x), CTRL, 0xf, 0xf, true);
    return x + __int_as_float(y);
}

// Sum over lanes 0..31 (lanes >=32 must carry zeros) -> wave-uniform.
__device__ __forceinline__ float wave_sum32(float x) {
    x = dpp_add<0xB1>(x);   // quad_perm [1,0,3,2] : xor 1
    x = dpp_add<0x4E>(x);   // quad_perm [2,3,0,1] : xor 2
    x = dpp_add<0x141>(x);  // row_half_mirror     : 8-group sums
    x = dpp_add<0x140>(x);  // row_mirror          : 16-row sums
    x = dpp_add<0x142>(x);  // row_bcast15         : lanes16-31 = lanes0-31 sum
    return rdlane(x, 31);
}

__global__ __launch_bounds__(256) void qr_mfma_r7(
    const float* __restrict__ in, float* __restrict__ out)
{
    const int lane = threadIdx.x & 63;
    const int wid  = threadIdx.x >> 6;
    const int b    = blockIdx.x * 4 + wid;

    // per-wave LDS: two u16 planes [16 cols][72 rows] (h, l), 4608 B/wave.
    // After the MFMA phase the same space is reused as the f32 G buffer.
    __shared__ __align__(16) char smem[4][2 * QC * 72 * 2];
    unsigned short* hp = reinterpret_cast<unsigned short*>(smem[wid]);
    unsigned short* lp = hp + QC * 72;

    const float4* __restrict__ A4 = (const float4*)(in  + (size_t)b * (DROWS * QC));
    float4*       __restrict__ O4 = (float4*)      (out + (size_t)b * (DROWS * QC));

    float x[4][QC];   // the matrix; becomes Q at the end

    // ---- load ----
#pragma unroll
    for (int s = 0; s < 4; ++s) {
        const int rr = s * 64 + lane;
#pragma unroll
        for (int q4 = 0; q4 < 4; ++q4) {
            float4 t = A4[rr * 4 + q4];
            x[s][q4*4+0] = t.x; x[s][q4*4+1] = t.y;
            x[s][q4*4+2] = t.z; x[s][q4*4+3] = t.w;
        }
    }

    // ---- G_bot via MFMA: stage split-f16 planes per 64-row slot, 8 K-chunks ----
    f32x4 accA = {0.f, 0.f, 0.f, 0.f};   // hh + ll chain
    f32x4 accB = {0.f, 0.f, 0.f, 0.f};   // hl + lh chain
    const int cm   = lane & 15;
    const int g4   = lane >> 4;
    const int fidx = cm * 72 + 8 * g4;   // u16 index of this lane's frag base

#pragma unroll
    for (int s = 0; s < 4; ++s) {
        // convert + scatter-write local row `lane` of this slot (mask rows<16)
#pragma unroll
        for (int c = 0; c < QC; ++c) {
            float v = x[s][c];
            if (s == 0) v = (lane < QC) ? 0.f : v;
            _Float16 hh = (_Float16)v;
            float     r = v - (float)hh;
            _Float16 ll = (_Float16)r;
            union { _Float16 f; unsigned short u; } ch, cl;
            ch.f = hh; cl.f = ll;
            hp[c * 72 + lane] = ch.u;
            lp[c * 72 + lane] = cl.u;
        }
        asm volatile("" ::: "memory");   // writes (u16) before frag reads (f16)
#pragma unroll
        for (int h = 0; h < 2; ++h) {
            const half8 fh = *reinterpret_cast<const half8*>(&hp[fidx + 32 * h]);
            const half8 fl = *reinterpret_cast<const half8*>(&lp[fidx + 32 * h]);
            accA = __builtin_amdgcn_mfma_f32_16x16x32_f16(fh, fh, accA, 0, 0, 0);
            accB = __builtin_amdgcn_mfma_f32_16x16x32_f16(fh, fl, accB, 0, 0, 0);
            accB = __builtin_amdgcn_mfma_f32_16x16x32_f16(fl, fh, accB, 0, 0, 0);
            accA = __builtin_amdgcn_mfma_f32_16x16x32_f16(fl, fl, accA, 0, 0, 0);
        }
        asm volatile("" ::: "memory");   // frag reads before next slot's writes
    }
    const f32x4 Gf = accA + accB;        // lane: G[4*g4+q][cm] (or transpose; G sym)

    // ---- scatter G to f32 buffer (pitch 20), gather row (lane&15) ----
    float* gbuf = reinterpret_cast<float*>(smem[wid]);
    asm volatile("" ::: "memory");
#pragma unroll
    for (int q = 0; q < 4; ++q) gbuf[(4 * g4 + q) * 20 + cm] = Gf[q];
    asm volatile("" ::: "memory");
    float g[QC];
#pragma unroll
    for (int k = 0; k < 4; ++k) {
        const f32x4 t = *reinterpret_cast<const f32x4*>(&gbuf[(lane & 15) * 20 + 4 * k]);
        g[4*k+0] = t[0]; g[4*k+1] = t[1]; g[4*k+2] = t[2]; g[4*k+3] = t[3];
    }

    const int li = lane - 16;   // cholesky row index for lanes 16..31

    // ---- Cholesky of G_bot (row i in lane 16+i; other lanes carry copies).
    //      Rows left unscaled; per-row scale rs = 1/sqrt(piv) applied at C build. ----
    float rs = 0.f;
#pragma unroll
    for (int k = 0; k < QC; ++k) {
        const float piv = rdlane(g[k], 16 + k);          // A^(k)[k][k]
        const float inv = __builtin_amdgcn_rcpf(piv);
        const float rsk = __builtin_amdgcn_rsqf(piv);
        rs = (li == k) ? rsk : rs;
        const float m = (li > k) ? g[k] * inv : 0.f;     // frozen rows -> no-op
#pragma unroll
        for (int j = k + 1; j < QC; ++j) {
            const float bj = rdlane(g[j], 16 + k);       // A^(k)[k][j] broadcast
            g[j] = fmaf(-m, bj, g[j]);
        }
    }

    // ---- C = [X_top ; U] in lanes 0..31 (lanes >=32 exactly zero) ----
    float c[QC];
#pragma unroll
    for (int t = 0; t < QC; ++t) {
        const float ub = (li <= t && li >= 0) ? g[t] * rs : 0.f;
        c[t] = (lane < QC) ? x[0][t] : ub;               // lanes>=32: li>15 -> 0
    }

    // column norms^2 of C (== column norms of X); downdated as rows freeze
    float nrm2[QC];
#pragma unroll
    for (int t = 0; t < QC; ++t) nrm2[t] = wave_sum32(c[t] * c[t]);

    // ---- Householder on C (32x16): leaves R embedded in c[] (lane r = row r) ----
#pragma unroll
    for (int j = 0; j < QC; ++j) {
        const float piv   = rdlane(c[j], j);
        const float nrm   = sqrtf(nrm2[j]);
        const float alpha = -copysignf(nrm, piv);            // LAPACK dlarfg sign
        const float vtv   = 2.f * (nrm2[j] - alpha * piv);   // ||v||^2, no cancel
        const float beta  = 2.f * __builtin_amdgcn_rcpf(vtv);
        // reflector (kept out of c[j] so frozen R rows i<j stay intact)
        const float v = (lane < j) ? 0.f : ((lane == j) ? piv - alpha : c[j]);
#pragma unroll
        for (int t = j + 1; t < QC; ++t) {
            const float d  = wave_sum32(v * c[t]);
            const float wb = beta * d;
            c[t] = fmaf(-wb, v, c[t]);
            const float rv = rdlane(c[t], j);                // R[j][t] frozen now
            nrm2[t] = fmaf(-rv, rv, nrm2[t]);
        }
        c[j] = (lane == j) ? alpha : c[j];                   // R[j][j]
    }

    // ---- Q = X R^{-1}: forward elimination, all-register, R via readlane ----
#pragma unroll
    for (int k = 0; k < QC; ++k) {
        const float rkk = rdlane(c[k], k);
        const float ikk = __builtin_amdgcn_rcpf(rkk);
        x[0][k] *= ikk; x[1][k] *= ikk; x[2][k] *= ikk; x[3][k] *= ikk;
#pragma unroll
        for (int t = k + 1; t < QC; ++t) {
            const float r = rdlane(c[t], k);                 // R[k][t]
            x[0][t] = fmaf(-r, x[0][k], x[0][t]);
            x[1][t] = fmaf(-r, x[1][k], x[1][t]);
            x[2][t] = fmaf(-r, x[2][k], x[2][t]);
            x[3][t] = fmaf(-r, x[3][k], x[3][t]);
        }
    }

    // ---- store ----
#pragma unroll
    for (int s = 0; s < 4; ++s) {
        const int rr = s * 64 + lane;
#pragma unroll
        for (int q4 = 0; q4 < 4; ++q4) {
            O4[rr * 4 + q4] = make_float4(x[s][q4*4+0], x[s][q4*4+1],
                                          x[s][q4*4+2], x[s][q4*4+3]);
        }
    }
}

extern "C" void kernel_launch(void* const* d_in, const int* in_sizes, int n_in,
                              void* d_out, int out_size, void* d_ws, size_t ws_size,
                              hipStream_t stream) {
    const float* X = (const float*)d_in[0];
    float*       O = (float*)d_out;
    qr_mfma_r7<<<BATCH / 4, 256, 0, stream>>>(X, O);
}

// Round 5
// 243.207 us; speedup vs baseline: 1.5023x; 1.0097x over previous
//
#include <hip/hip_runtime.h>

// Batched thin QR (LAPACK sign convention) for 8192 x (256x16) fp32.
// One 64-lane wave per matrix; lane l owns rows {l, l+64, l+128, l+192}.
//
// Round-8: dual-column reductions for the Householder phase.
//   r7 (verified): Gram via split-f16 MFMA; chol(G_bot) -> C=[X_top;U] (32x16);
//   HH on C reproduces LAPACK pivots/signs/R; Q = X R^{-1} in registers.
//   New here: C is MIRRORED across lane halves (lane l and l+32 identical,
//   via 16 one-time ds_bpermute; updates use wave-uniform scalars so the
//   mirror self-maintains). row_bcast15 yields the lanes0-31 sum in lanes
//   16-31 AND the lanes32-63 sum in lanes 48-63 (dual behavior HW-proven by
//   our passing wave_sum64), so ONE 5-DPP chain reduces TWO columns:
//   lanes0-31 dot col t, lanes32-63 dot col t+1. HH t-loop and the 16 norm
//   reductions run in pairs -> 136 -> 72 reduction chains.

constexpr int BATCH = 8192;
constexpr int DROWS = 256;
constexpr int QC    = 16;

typedef _Float16 half8 __attribute__((ext_vector_type(8)));
typedef float    f32x4 __attribute__((ext_vector_type(4)));

__device__ __forceinline__ float rdlane(float v, int l) {
    return __int_as_float(__builtin_amdgcn_readlane(__float_as_int(v), l));
}

template <int CTRL>
__device__ __forceinline__ float dpp_add(float x) {
    int y = __builtin_amdgcn_update_dpp(0, __float_as_int(x), CTRL, 0xf, 0xf, true);
    return x + __int_as_float(y);
}

// Sum over lanes 0..31 (upper half may hold garbage) -> wave-uniform.
__device__ __forceinline__ float wave_sum32(float x) {
    x = dpp_add<0xB1>(x);   // quad_perm [1,0,3,2] : xor 1
    x = dpp_add<0x4E>(x);   // quad_perm [2,3,0,1] : xor 2
    x = dpp_add<0x141>(x);  // row_half_mirror     : 8-group sums
    x = dpp_add<0x140>(x);  // row_mirror          : 16-row sums
    x = dpp_add<0x142>(x);  // row_bcast15         : lanes16-31 = r0+r1
    return rdlane(x, 31);
}

// TWO independent sums with one chain: lanes0-31 -> .x, lanes32-63 -> .y.
__device__ __forceinline__ float2 dual_sum32(float x) {
    x = dpp_add<0xB1>(x);
    x = dpp_add<0x4E>(x);
    x = dpp_add<0x141>(x);
    x = dpp_add<0x140>(x);  // each 16-row holds its row sum
    x = dpp_add<0x142>(x);  // bcast15: lanes16-31 = r0+r1, lanes48-63 = r2+r3
    return make_float2(rdlane(x, 31), rdlane(x, 63));
}

__global__ __launch_bounds__(256) void qr_dual_r8(
    const float* __restrict__ in, float* __restrict__ out)
{
    const int lane = threadIdx.x & 63;
    const int wid  = threadIdx.x >> 6;
    const int b    = blockIdx.x * 4 + wid;

    // per-wave LDS: two u16 planes [16 cols][72 rows] (h, l), 4608 B/wave.
    // After the MFMA phase the same space is reused as the f32 G buffer.
    __shared__ __align__(16) char smem[4][2 * QC * 72 * 2];
    unsigned short* hp = reinterpret_cast<unsigned short*>(smem[wid]);
    unsigned short* lp = hp + QC * 72;

    const float4* __restrict__ A4 = (const float4*)(in  + (size_t)b * (DROWS * QC));
    float4*       __restrict__ O4 = (float4*)      (out + (size_t)b * (DROWS * QC));

    float x[4][QC];   // the matrix; becomes Q at the end

    // ---- load ----
#pragma unroll
    for (int s = 0; s < 4; ++s) {
        const int rr = s * 64 + lane;
#pragma unroll
        for (int q4 = 0; q4 < 4; ++q4) {
            float4 t = A4[rr * 4 + q4];
            x[s][q4*4+0] = t.x; x[s][q4*4+1] = t.y;
            x[s][q4*4+2] = t.z; x[s][q4*4+3] = t.w;
        }
    }

    // ---- G_bot via MFMA: stage split-f16 planes per 64-row slot, 8 K-chunks ----
    f32x4 accA = {0.f, 0.f, 0.f, 0.f};   // hh + ll chain
    f32x4 accB = {0.f, 0.f, 0.f, 0.f};   // hl + lh chain
    const int cm   = lane & 15;
    const int g4   = lane >> 4;
    const int fidx = cm * 72 + 8 * g4;   // u16 index of this lane's frag base

#pragma unroll
    for (int s = 0; s < 4; ++s) {
        // convert + scatter-write local row `lane` of this slot (mask rows<16)
#pragma unroll
        for (int c = 0; c < QC; ++c) {
            float v = x[s][c];
            if (s == 0) v = (lane < QC) ? 0.f : v;
            _Float16 hh = (_Float16)v;
            float     r = v - (float)hh;
            _Float16 ll = (_Float16)r;
            union { _Float16 f; unsigned short u; } ch, cl;
            ch.f = hh; cl.f = ll;
            hp[c * 72 + lane] = ch.u;
            lp[c * 72 + lane] = cl.u;
        }
        asm volatile("" ::: "memory");   // writes (u16) before frag reads (f16)
#pragma unroll
        for (int h = 0; h < 2; ++h) {
            const half8 fh = *reinterpret_cast<const half8*>(&hp[fidx + 32 * h]);
            const half8 fl = *reinterpret_cast<const half8*>(&lp[fidx + 32 * h]);
            accA = __builtin_amdgcn_mfma_f32_16x16x32_f16(fh, fh, accA, 0, 0, 0);
            accB = __builtin_amdgcn_mfma_f32_16x16x32_f16(fh, fl, accB, 0, 0, 0);
            accB = __builtin_amdgcn_mfma_f32_16x16x32_f16(fl, fh, accB, 0, 0, 0);
            accA = __builtin_amdgcn_mfma_f32_16x16x32_f16(fl, fl, accA, 0, 0, 0);
        }
        asm volatile("" ::: "memory");   // frag reads before next slot's writes
    }
    const f32x4 Gf = accA + accB;        // lane: G[4*g4+q][cm] (or transpose; G sym)

    // ---- scatter G to f32 buffer (pitch 20), gather row (lane&15) ----
    float* gbuf = reinterpret_cast<float*>(smem[wid]);
    asm volatile("" ::: "memory");
#pragma unroll
    for (int q = 0; q < 4; ++q) gbuf[(4 * g4 + q) * 20 + cm] = Gf[q];
    asm volatile("" ::: "memory");
    float g[QC];
#pragma unroll
    for (int k = 0; k < 4; ++k) {
        const f32x4 t = *reinterpret_cast<const f32x4*>(&gbuf[(lane & 15) * 20 + 4 * k]);
        g[4*k+0] = t[0]; g[4*k+1] = t[1]; g[4*k+2] = t[2]; g[4*k+3] = t[3];
    }

    const int li = lane - 16;   // cholesky row index for lanes 16..31

    // ---- Cholesky of G_bot (row i in lane 16+i; other lanes carry copies).
    //      Rows left unscaled; per-row scale rs = 1/sqrt(piv) applied at C build. ----
    float rs = 0.f;
#pragma unroll
    for (int k = 0; k < QC; ++k) {
        const float piv = rdlane(g[k], 16 + k);          // A^(k)[k][k]
        const float inv = __builtin_amdgcn_rcpf(piv);
        const float rsk = __builtin_amdgcn_rsqf(piv);
        rs = (li == k) ? rsk : rs;
        const float m = (li > k) ? g[k] * inv : 0.f;     // frozen rows -> no-op
#pragma unroll
        for (int j = k + 1; j < QC; ++j) {
            const float bj = rdlane(g[j], 16 + k);       // A^(k)[k][j] broadcast
            g[j] = fmaf(-m, bj, g[j]);
        }
    }

    // ---- C = [X_top ; U] built in lanes 0..31, then MIRRORED into 32..63 ----
    float c[QC];
#pragma unroll
    for (int t = 0; t < QC; ++t) {
        const float ub = (li <= t && li >= 0) ? g[t] * rs : 0.f;
        c[t] = (lane < QC) ? x[0][t] : ub;
    }
    const int baddr = (lane & 31) << 2;   // bpermute: lanes 32-63 pull lanes 0-31
#pragma unroll
    for (int t = 0; t < QC; ++t)
        c[t] = __int_as_float(__builtin_amdgcn_ds_bpermute(baddr, __float_as_int(c[t])));

    const bool hi  = (lane >= 32);
    const int  row = lane & 31;           // mirrored row index

    // column norms^2 of C (== column norms of X), two per chain
    float nrm2[QC];
#pragma unroll
    for (int m = 0; m < QC; m += 2) {
        const float pc = hi ? c[m + 1] : c[m];
        const float2 ss = dual_sum32(pc * pc);
        nrm2[m] = ss.x; nrm2[m + 1] = ss.y;
    }

    // ---- Householder on C (32x16), paired trailing columns ----
#pragma unroll
    for (int j = 0; j < QC; ++j) {
        const float piv   = rdlane(c[j], j);
        const float nrm   = sqrtf(nrm2[j]);
        const float alpha = -copysignf(nrm, piv);            // LAPACK dlarfg sign
        const float vtv   = 2.f * (nrm2[j] - alpha * piv);   // ||v||^2, no cancel
        const float beta  = 2.f * __builtin_amdgcn_rcpf(vtv);
        // reflector, mirrored across halves (c mirrored, conditions on row)
        const float v = (row < j) ? 0.f : ((row == j) ? piv - alpha : c[j]);
        int t = j + 1;
#pragma unroll
        for (; t + 1 < QC; t += 2) {
            const float pc = hi ? c[t + 1] : c[t];
            const float2 d = dual_sum32(v * pc);
            const float wb0 = beta * d.x;
            const float wb1 = beta * d.y;
            c[t]     = fmaf(-wb0, v, c[t]);
            c[t + 1] = fmaf(-wb1, v, c[t + 1]);
            const float rv0 = rdlane(c[t], j);               // R[j][t] frozen now
            const float rv1 = rdlane(c[t + 1], j);
            nrm2[t]     = fmaf(-rv0, rv0, nrm2[t]);
            nrm2[t + 1] = fmaf(-rv1, rv1, nrm2[t + 1]);
        }
        if (t < QC) {                                        // odd tail column
            const float d  = wave_sum32(v * c[t]);
            const float wb = beta * d;
            c[t] = fmaf(-wb, v, c[t]);
            const float rv = rdlane(c[t], j);
            nrm2[t] = fmaf(-rv, rv, nrm2[t]);
        }
        c[j] = (row == j) ? alpha : c[j];                    // R[j][j] (mirrored)
    }

    // ---- Q = X R^{-1}: forward elimination, all-register, R via readlane ----
#pragma unroll
    for (int k = 0; k < QC; ++k) {
        const float rkk = rdlane(c[k], k);
        const float ikk = __builtin_amdgcn_rcpf(rkk);
        x[0][k] *= ikk; x[1][k] *= ikk; x[2][k] *= ikk; x[3][k] *= ikk;
#pragma unroll
        for (int t = k + 1; t < QC; ++t) {
            const float r = rdlane(c[t], k);                 // R[k][t]
            x[0][t] = fmaf(-r, x[0][k], x[0][t]);
            x[1][t] = fmaf(-r, x[1][k], x[1][t]);
            x[2][t] = fmaf(-r, x[2][k], x[2][t]);
            x[3][t] = fmaf(-r, x[3][k], x[3][t]);
        }
    }

    // ---- store ----
#pragma unroll
    for (int s = 0; s < 4; ++s) {
        const int rr = s * 64 + lane;
#pragma unroll
        for (int q4 = 0; q4 < 4; ++q4) {
            O4[rr * 4 + q4] = make_float4(x[s][q4*4+0], x[s][q4*4+1],
                                          x[s][q4*4+2], x[s][q4*4+3]);
        }
    }
}

extern "C" void kernel_launch(void* const* d_in, const int* in_sizes, int n_in,
                              void* d_out, int out_size, void* d_ws, size_t ws_size,
                              hipStream_t stream) {
    const float* X = (const float*)d_in[0];
    float*       O = (float*)d_out;
    qr_dual_r8<<<BATCH / 4, 256, 0, stream>>>(X, O);
}